// Round 9
// baseline (66.779 us; speedup 1.0000x reference)
//
#include <hip/hip_runtime.h>
#include <hip/hip_fp16.h>

#define IMG 224
#define PLANE (IMG * IMG)        // 50176
#define BANDROWS 14
#define NBANDS 16                // 16 * 14 = 224
#define NWAVES (256 * NBANDS)    // 4096 waves
#define NPBLK (NWAVES / 4)       // 1024 blocks of 4 waves
#define GROUPS_PER_IMG (PLANE / 4)   // 12544 4-px groups

typedef float fl4 __attribute__((ext_vector_type(4)));

// ws layout: [0,16) red u32[4] | [64, +16KB) partials uint4[NPBLK]
//            [65536, +51.4MB) cmb: per-4px-group uint4 {rec01,rec23,ves01,ves23}
#define WS_CMB_OFF 65536
#define WS_NEED (WS_CMB_OFF + (size_t)256 * PLANE * 4)

// ---- ordered-uint mapping for float min/max ----
__device__ __forceinline__ unsigned int ford(float f) {
    unsigned int u = __float_as_uint(f);
    return (u & 0x80000000u) ? ~u : (u | 0x80000000u);
}
__device__ __forceinline__ float funord(unsigned int u) {
    unsigned int v = (u & 0x80000000u) ? (u & 0x7FFFFFFFu) : ~u;
    return __uint_as_float(v);
}

// MODE 0: minmax only -> partials          (fallback pass 1)
// MODE 1: minmax + ch0 + packed fp16 store (fast pass 1)
// MODE 2: recompute + write all 3 channels (fallback pass 2, reads red)
template<int MODE>
__global__ __launch_bounds__(256)
void band_kernel(const float* __restrict__ x, float* __restrict__ out,
                 uint4* __restrict__ cmb4, uint4* __restrict__ partials,
                 const unsigned int* __restrict__ red)
{
    const int wid  = (blockIdx.x << 2) + (threadIdx.x >> 6);
    const int lane = threadIdx.x & 63;
    const int img  = wid >> 4;
    const int band = wid & 15;
    const int r0   = band * BANDROWS;
    const bool active = lane < 56;
    const int col = lane * 4;
    const float* xp = x + (size_t)img * 3 * PLANE;

    float rmin = 0.f, rsc = 0.f, vmin = 0.f, vsc = 0.f;
    if constexpr (MODE == 2) {
        rmin = funord(red[0]); const float rmax = funord(red[1]);
        vmin = funord(red[2]); const float vmax = funord(red[3]);
        rsc = 1.f / (rmax - rmin + 1e-6f);
        vsc = 1.f / (vmax - vmin + 1e-6f);
    }
    const float m0 = 0.485f, i0 = 1.f / 0.229f;
    const float m1 = 0.456f, i1 = 1.f / 0.224f;
    const float m2 = 0.406f, i2 = 1.f / 0.225f;

    float rmn = 3.4e38f, rmx = -3.4e38f, vmn = 3.4e38f, vmx = -3.4e38f;

    auto loadrow = [&](int gr) -> fl4 {
        fl4 v = (fl4)0.f;
        if (active && (unsigned)gr < (unsigned)IMG)
            v = *(const fl4*)(xp + gr * IMG + col);
        return v;
    };

    // horizontal prefilters: uu = [1,0,-2,0,1]*x, ww = [1,4,6,4,1]*x (zero-pad)
    auto pref = [&](fl4 p, fl4& uu, fl4& ww) {
        float cl1 = __shfl_up(p[3], 1);
        float cl2 = __shfl_up(p[2], 1);
        float cr1 = __shfl_down(p[0], 1);   // lane56 p==0 -> right pad free
        float cr2 = __shfl_down(p[1], 1);
        if (lane == 0) { cl1 = 0.f; cl2 = 0.f; }
        uu[0] = cl2 - 2.f*p[0] + p[2];
        uu[1] = cl1 - 2.f*p[1] + p[3];
        uu[2] = p[0] - 2.f*p[2] + cr1;
        uu[3] = p[1] - 2.f*p[3] + cr2;
        ww[0] = cl2 + 4.f*cl1 + 6.f*p[0] + 4.f*p[1] + p[2];
        ww[1] = cl1 + 4.f*p[0] + 6.f*p[1] + 4.f*p[2] + p[3];
        ww[2] = p[0] + 4.f*p[1] + 6.f*p[2] + 4.f*p[3] + cr1;
        ww[3] = p[1] + 4.f*p[2] + 6.f*p[3] + 4.f*cr1 + cr2;
    };

    auto haar2 = [&](fl4 xe, fl4 xo, fl4& re_, fl4& ro_) {
        #pragma unroll
        for (int q = 0; q < 2; ++q) {
            const float a = xe[2*q], b = xe[2*q+1], c = xo[2*q], d = xo[2*q+1];
            const float h0 = (a+b+c+d)*0.5f, h1 = (a-b+c-d)*0.5f;
            const float h2 = (a+b-c-d)*0.5f, h3 = (a-b-c+d)*0.5f;
            const float s0 = 0.1f*h0, s1 = 2.5f*h1, s2 = 2.5f*h2, s3 = 3.5f*h3;
            re_[2*q]   = (s0+s1+s2+s3)*0.5f;
            re_[2*q+1] = (s0-s1+s2-s3)*0.5f;
            ro_[2*q]   = (s0+s1-s2-s3)*0.5f;
            ro_[2*q+1] = (s0-s1-s2+s3)*0.5f;
        }
    };

    // emit one output row (closed-form border corrections, validated R8)
    auto dorow = [&](int gr, fl4 ua, fl4 ub, fl4 uc, fl4 ud, fl4 ue,
                     fl4 wa, fl4 wb, fl4 wc, fl4 wd, fl4 we,
                     fl4 pm1, fl4 p0c, fl4 pp1, fl4 recv) {
        fl4 t;
        #pragma unroll
        for (int j = 0; j < 4; ++j)
            t[j] = ua[j] + 4.f*ub[j] + 6.f*uc[j] + 4.f*ud[j] + ue[j]
                 + wa[j] - 2.f*wc[j] + we[j];
        const bool rb = (gr == 0) | (gr == IMG - 1);
        if (rb) {
            #pragma unroll
            for (int j = 0; j < 4; ++j) t[j] -= (uc[j] - wc[j]);
        }
        const float corr0 = -4.f*(pm1[0] + 2.f*p0c[0] + pp1[0]);
        const float corr3 = -4.f*(pm1[3] + 2.f*p0c[3] + pp1[3]);
        if (lane == 0)  t[0] -= corr0 + (rb ? 2.f*p0c[0] : 0.f);
        if (lane == 55) t[3] -= corr3 + (rb ? 2.f*p0c[3] : 0.f);
        fl4 ves;
        #pragma unroll
        for (int j = 0; j < 4; ++j) ves[j] = fabsf(t[j]);

        if (active) {
            #pragma unroll
            for (int j = 0; j < 4; ++j) {
                rmn = fminf(rmn, recv[j]); rmx = fmaxf(rmx, recv[j]);
                vmn = fminf(vmn, ves[j]);  vmx = fmaxf(vmx, ves[j]);
            }
            if constexpr (MODE == 1) {
                float* op = out + (size_t)img * 3 * PLANE + gr * IMG + col;
                fl4 o0;
                #pragma unroll
                for (int j = 0; j < 4; ++j) o0[j] = (p0c[j] - m0) * i0;
                *(fl4*)op = o0;
                uint4 c;
                c.x = __builtin_bit_cast(unsigned int, __floats2half2_rn(recv[0], recv[1]));
                c.y = __builtin_bit_cast(unsigned int, __floats2half2_rn(recv[2], recv[3]));
                c.z = __builtin_bit_cast(unsigned int, __floats2half2_rn(ves[0], ves[1]));
                c.w = __builtin_bit_cast(unsigned int, __floats2half2_rn(ves[2], ves[3]));
                cmb4[(size_t)img * GROUPS_PER_IMG + gr * (IMG / 4) + lane] = c;
            }
            if constexpr (MODE == 2) {
                float* op = out + (size_t)img * 3 * PLANE + gr * IMG + col;
                fl4 o0, o1, o2;
                #pragma unroll
                for (int j = 0; j < 4; ++j) {
                    o0[j] = (p0c[j] - m0) * i0;
                    o1[j] = ((recv[j] - rmin) * rsc - m1) * i1;
                    o2[j] = ((ves[j]  - vmin) * vsc - m2) * i2;
                }
                *(fl4*)op               = o0;
                *(fl4*)(op + PLANE)     = o1;
                *(fl4*)(op + 2 * PLANE) = o2;
            }
        }
    };

    // ---- warm-up rows r0-2 .. r0+1 ----
    fl4 uA, uB, uC, uD, wA, wB, wC, wD, pB, pC, pD;
    {
        fl4 pA = loadrow(r0 - 2); pref(pA, uA, wA);
        pB = loadrow(r0 - 1); pref(pB, uB, wB);
        pC = loadrow(r0);     pref(pC, uC, wC);
        pD = loadrow(r0 + 1); pref(pD, uD, wD);
    }

    // ---- march 7 row-pairs ----
    for (int k = 0; k < 7; ++k) {
        const int re = r0 + 2 * k;
        fl4 pE = loadrow(re + 2); fl4 uE, wE; pref(pE, uE, wE);
        fl4 rec_e, rec_o; haar2(pC, pD, rec_e, rec_o);
        dorow(re,     uA, uB, uC, uD, uE, wA, wB, wC, wD, wE, pB, pC, pD, rec_e);
        fl4 pF = loadrow(re + 3); fl4 uF, wF; pref(pF, uF, wF);
        dorow(re + 1, uB, uC, uD, uE, uF, wB, wC, wD, wE, wF, pC, pD, pE, rec_o);
        uA = uC; uB = uD; uC = uE; uD = uF;
        wA = wC; wB = wD; wC = wE; wD = wF;
        pB = pD; pC = pE; pD = pF;
    }

    if constexpr (MODE != 2) {
        #pragma unroll
        for (int off = 32; off; off >>= 1) {
            rmn = fminf(rmn, __shfl_down(rmn, off));
            rmx = fmaxf(rmx, __shfl_down(rmx, off));
            vmn = fminf(vmn, __shfl_down(vmn, off));
            vmx = fmaxf(vmx, __shfl_down(vmx, off));
        }
        __shared__ uint4 wred[4];
        if (lane == 0) {
            uint4 p;
            p.x = ford(rmn); p.y = ford(rmx); p.z = ford(vmn); p.w = ford(vmx);
            wred[threadIdx.x >> 6] = p;
        }
        __syncthreads();
        if (threadIdx.x == 0) {
            uint4 p = wred[0];
            #pragma unroll
            for (int w = 1; w < 4; ++w) {
                p.x = min(p.x, wred[w].x); p.y = max(p.y, wred[w].y);
                p.z = min(p.z, wred[w].z); p.w = max(p.w, wred[w].w);
            }
            partials[blockIdx.x] = p;
        }
    }
}

// Reduce NPBLK uint4 partials -> red[0..3].
__global__ __launch_bounds__(256)
void reduce_partials(const uint4* __restrict__ partials, unsigned int* __restrict__ red)
{
    __shared__ unsigned int wred[4][4];
    const int tid = threadIdx.x;
    unsigned int mn0 = 0xFFFFFFFFu, mx1 = 0u, mn2 = 0xFFFFFFFFu, mx3 = 0u;
    for (int i = tid; i < NPBLK; i += 256) {
        uint4 p = partials[i];
        mn0 = min(mn0, p.x); mx1 = max(mx1, p.y);
        mn2 = min(mn2, p.z); mx3 = max(mx3, p.w);
    }
    #pragma unroll
    for (int off = 32; off; off >>= 1) {
        mn0 = min(mn0, (unsigned)__shfl_down((int)mn0, off));
        mx1 = max(mx1, (unsigned)__shfl_down((int)mx1, off));
        mn2 = min(mn2, (unsigned)__shfl_down((int)mn2, off));
        mx3 = max(mx3, (unsigned)__shfl_down((int)mx3, off));
    }
    const int wave = tid >> 6;
    if ((tid & 63) == 0) {
        wred[wave][0] = mn0; wred[wave][1] = mx1;
        wred[wave][2] = mn2; wred[wave][3] = mx3;
    }
    __syncthreads();
    if (tid == 0) {
        unsigned int a0 = wred[0][0], a1 = wred[0][1], a2 = wred[0][2], a3 = wred[0][3];
        #pragma unroll
        for (int w = 1; w < 4; ++w) {
            a0 = min(a0, wred[w][0]); a1 = max(a1, wred[w][1]);
            a2 = min(a2, wred[w][2]); a3 = max(a3, wred[w][3]);
        }
        red[0] = a0; red[1] = a1; red[2] = a2; red[3] = a3;
    }
}

// Fast pass 2: pure affine over packed fp16 groups. 12544 blocks x 256 thr,
// 1 uint4 load -> 2 fl4 stores per thread.
__global__ __launch_bounds__(256)
void affine_kernel(const uint4* __restrict__ cmb4, float* __restrict__ out,
                   const unsigned int* __restrict__ red)
{
    const int g   = blockIdx.x * 256 + threadIdx.x;     // 4-px group id
    const int img = g / GROUPS_PER_IMG;
    const int o4  = g - img * GROUPS_PER_IMG;

    const float rmin = funord(red[0]), rmax = funord(red[1]);
    const float vmin = funord(red[2]), vmax = funord(red[3]);
    const float rsc = 1.f / (rmax - rmin + 1e-6f);
    const float vsc = 1.f / (vmax - vmin + 1e-6f);
    const float m1 = 0.456f, i1 = 1.f / 0.224f;
    const float m2 = 0.406f, i2 = 1.f / 0.225f;

    const uint4 c = cmb4[g];
    const float2 r01 = __half22float2(__builtin_bit_cast(__half2, c.x));
    const float2 r23 = __half22float2(__builtin_bit_cast(__half2, c.y));
    const float2 v01 = __half22float2(__builtin_bit_cast(__half2, c.z));
    const float2 v23 = __half22float2(__builtin_bit_cast(__half2, c.w));

    fl4 o1, o2;
    o1[0] = ((r01.x - rmin) * rsc - m1) * i1;
    o1[1] = ((r01.y - rmin) * rsc - m1) * i1;
    o1[2] = ((r23.x - rmin) * rsc - m1) * i1;
    o1[3] = ((r23.y - rmin) * rsc - m1) * i1;
    o2[0] = ((v01.x - vmin) * vsc - m2) * i2;
    o2[1] = ((v01.y - vmin) * vsc - m2) * i2;
    o2[2] = ((v23.x - vmin) * vsc - m2) * i2;
    o2[3] = ((v23.y - vmin) * vsc - m2) * i2;

    float* base = out + (size_t)img * 3 * PLANE + PLANE + o4 * 4;
    *(fl4*)base           = o1;
    *(fl4*)(base + PLANE) = o2;
}

extern "C" void kernel_launch(void* const* d_in, const int* in_sizes, int n_in,
                              void* d_out, int out_size, void* d_ws, size_t ws_size,
                              hipStream_t stream) {
    const float* x = (const float*)d_in[0];
    float* out = (float*)d_out;
    unsigned int* red = (unsigned int*)d_ws;
    uint4* partials = (uint4*)((char*)d_ws + 64);
    uint4* cmb4 = (uint4*)((char*)d_ws + WS_CMB_OFF);

    if (ws_size >= WS_NEED) {
        band_kernel<1><<<dim3(NPBLK), 256, 0, stream>>>(x, out, cmb4, partials, nullptr);
        reduce_partials<<<1, 256, 0, stream>>>(partials, red);
        affine_kernel<<<dim3(256 * GROUPS_PER_IMG / 256), 256, 0, stream>>>(cmb4, out, red);
    } else {
        band_kernel<0><<<dim3(NPBLK), 256, 0, stream>>>(x, nullptr, nullptr, partials, nullptr);
        reduce_partials<<<1, 256, 0, stream>>>(partials, red);
        band_kernel<2><<<dim3(NPBLK), 256, 0, stream>>>(x, out, nullptr, nullptr, red);
    }
}

// Round 10
// 58.099 us; speedup vs baseline: 1.1494x; 1.1494x over previous
//
#include <hip/hip_runtime.h>

#define IMG 224
#define PLANE (IMG * IMG)        // 50176
#define BANDROWS 14
#define NBANDS 16                // 16 * 14 = 224
#define NWAVES (256 * NBANDS)    // 4096 waves
#define NPBLK (NWAVES / 4)       // 1024 blocks of 4 waves

typedef float fl4 __attribute__((ext_vector_type(4)));

// ws layout: [0,16) red u32[4] | [64, +16KB) partials uint4[NPBLK]

// ---- ordered-uint mapping for float min/max ----
__device__ __forceinline__ unsigned int ford(float f) {
    unsigned int u = __float_as_uint(f);
    return (u & 0x80000000u) ? ~u : (u | 0x80000000u);
}
__device__ __forceinline__ float funord(unsigned int u) {
    unsigned int v = (u & 0x80000000u) ? (u & 0x7FFFFFFFu) : ~u;
    return __uint_as_float(v);
}

// One wave = one 14-row band of one image. Lane L owns cols 4L..4L+3 (L<56).
// No LDS in the hot loop, no barriers; horizontal halo via __shfl, vertical
// window via register rings; loads double-buffered one row-pair ahead.
// Border-exactness via closed-form corrections (validated R8).
// MODE 0: pass1 — min/max partials + ch0 write.
// MODE 1: pass2 — rec/ves channels write (reads red).
template<int MODE>
__global__ __launch_bounds__(256)
void band_kernel(const float* __restrict__ x, float* __restrict__ out,
                 uint4* __restrict__ partials, const unsigned int* __restrict__ red)
{
    const int wid  = (blockIdx.x << 2) + (threadIdx.x >> 6);
    const int lane = threadIdx.x & 63;
    const int img  = wid >> 4;
    const int band = wid & 15;
    const int r0   = band * BANDROWS;
    const bool active = lane < 56;
    const int col = lane * 4;
    const float* xp = x + (size_t)img * 3 * PLANE;

    float rmin = 0.f, rsc = 0.f, vmin = 0.f, vsc = 0.f;
    if constexpr (MODE == 1) {
        rmin = funord(red[0]); const float rmax = funord(red[1]);
        vmin = funord(red[2]); const float vmax = funord(red[3]);
        rsc = 1.f / (rmax - rmin + 1e-6f);
        vsc = 1.f / (vmax - vmin + 1e-6f);
    }
    const float m0 = 0.485f, i0 = 1.f / 0.229f;
    const float m1 = 0.456f, i1 = 1.f / 0.224f;
    const float m2 = 0.406f, i2 = 1.f / 0.225f;

    float rmn = 3.4e38f, rmx = -3.4e38f, vmn = 3.4e38f, vmx = -3.4e38f;

    auto loadrow = [&](int gr) -> fl4 {
        fl4 v = (fl4)0.f;
        if (active && (unsigned)gr < (unsigned)IMG)
            v = *(const fl4*)(xp + gr * IMG + col);
        return v;
    };

    // horizontal prefilters: uu = [1,0,-2,0,1]*x, ww = [1,4,6,4,1]*x (zero-pad)
    auto pref = [&](fl4 p, fl4& uu, fl4& ww) {
        float cl1 = __shfl_up(p[3], 1);
        float cl2 = __shfl_up(p[2], 1);
        float cr1 = __shfl_down(p[0], 1);   // lane56 p==0 -> right pad free
        float cr2 = __shfl_down(p[1], 1);
        if (lane == 0) { cl1 = 0.f; cl2 = 0.f; }
        uu[0] = cl2 - 2.f*p[0] + p[2];
        uu[1] = cl1 - 2.f*p[1] + p[3];
        uu[2] = p[0] - 2.f*p[2] + cr1;
        uu[3] = p[1] - 2.f*p[3] + cr2;
        ww[0] = cl2 + 4.f*cl1 + 6.f*p[0] + 4.f*p[1] + p[2];
        ww[1] = cl1 + 4.f*p[0] + 6.f*p[1] + 4.f*p[2] + p[3];
        ww[2] = p[0] + 4.f*p[1] + 6.f*p[2] + 4.f*p[3] + cr1;
        ww[3] = p[1] + 4.f*p[2] + 6.f*p[3] + 4.f*cr1 + cr2;
    };

    auto haar2 = [&](fl4 xe, fl4 xo, fl4& re_, fl4& ro_) {
        #pragma unroll
        for (int q = 0; q < 2; ++q) {
            const float a = xe[2*q], b = xe[2*q+1], c = xo[2*q], d = xo[2*q+1];
            const float h0 = (a+b+c+d)*0.5f, h1 = (a-b+c-d)*0.5f;
            const float h2 = (a+b-c-d)*0.5f, h3 = (a-b-c+d)*0.5f;
            const float s0 = 0.1f*h0, s1 = 2.5f*h1, s2 = 2.5f*h2, s3 = 3.5f*h3;
            re_[2*q]   = (s0+s1+s2+s3)*0.5f;
            re_[2*q+1] = (s0-s1+s2-s3)*0.5f;
            ro_[2*q]   = (s0+s1-s2-s3)*0.5f;
            ro_[2*q+1] = (s0-s1-s2+s3)*0.5f;
        }
    };

    // emit one output row (closed-form border corrections, validated R8)
    auto dorow = [&](int gr, fl4 ua, fl4 ub, fl4 uc, fl4 ud, fl4 ue,
                     fl4 wa, fl4 wb, fl4 wc, fl4 wd, fl4 we,
                     fl4 pm1, fl4 p0c, fl4 pp1, fl4 recv) {
        fl4 t;
        #pragma unroll
        for (int j = 0; j < 4; ++j)
            t[j] = ua[j] + 4.f*ub[j] + 6.f*uc[j] + 4.f*ud[j] + ue[j]
                 + wa[j] - 2.f*wc[j] + we[j];
        const bool rb = (gr == 0) | (gr == IMG - 1);
        if (rb) {
            #pragma unroll
            for (int j = 0; j < 4; ++j) t[j] -= (uc[j] - wc[j]);
        }
        const float corr0 = -4.f*(pm1[0] + 2.f*p0c[0] + pp1[0]);
        const float corr3 = -4.f*(pm1[3] + 2.f*p0c[3] + pp1[3]);
        if (lane == 0)  t[0] -= corr0 + (rb ? 2.f*p0c[0] : 0.f);
        if (lane == 55) t[3] -= corr3 + (rb ? 2.f*p0c[3] : 0.f);
        fl4 ves;
        #pragma unroll
        for (int j = 0; j < 4; ++j) ves[j] = fabsf(t[j]);

        if (active) {
            if constexpr (MODE == 0) {
                #pragma unroll
                for (int j = 0; j < 4; ++j) {
                    rmn = fminf(rmn, recv[j]); rmx = fmaxf(rmx, recv[j]);
                    vmn = fminf(vmn, ves[j]);  vmx = fmaxf(vmx, ves[j]);
                }
                float* op = out + (size_t)img * 3 * PLANE + gr * IMG + col;
                fl4 o0;
                #pragma unroll
                for (int j = 0; j < 4; ++j) o0[j] = (p0c[j] - m0) * i0;
                *(fl4*)op = o0;
            } else {
                float* op = out + (size_t)img * 3 * PLANE + gr * IMG + col;
                fl4 o1, o2;
                #pragma unroll
                for (int j = 0; j < 4; ++j) {
                    o1[j] = ((recv[j] - rmin) * rsc - m1) * i1;
                    o2[j] = ((ves[j]  - vmin) * vsc - m2) * i2;
                }
                *(fl4*)(op + PLANE)     = o1;
                *(fl4*)(op + 2 * PLANE) = o2;
            }
        }
    };

    // ---- warm-up rows r0-2 .. r0+1, plus next-pair prefetch ----
    fl4 uA, uB, uC, uD, wA, wB, wC, wD, pB, pC, pD, nE, nF;
    {
        fl4 pA = loadrow(r0 - 2); pref(pA, uA, wA);
        pB = loadrow(r0 - 1); pref(pB, uB, wB);
        pC = loadrow(r0);     pref(pC, uC, wC);
        pD = loadrow(r0 + 1); pref(pD, uD, wD);
        nE = loadrow(r0 + 2);
        nF = loadrow(r0 + 3);
    }

    // ---- march 7 row-pairs, loads one pair ahead ----
    for (int k = 0; k < 7; ++k) {
        const int re = r0 + 2 * k;
        const fl4 pE = nE, pF = nF;
        if (k < 6) {                       // issue k+1's loads before compute
            nE = loadrow(re + 4);
            nF = loadrow(re + 5);
        }
        fl4 uE, wE; pref(pE, uE, wE);
        fl4 rec_e, rec_o; haar2(pC, pD, rec_e, rec_o);
        dorow(re,     uA, uB, uC, uD, uE, wA, wB, wC, wD, wE, pB, pC, pD, rec_e);
        fl4 uF, wF; pref(pF, uF, wF);
        dorow(re + 1, uB, uC, uD, uE, uF, wB, wC, wD, wE, wF, pC, pD, pE, rec_o);
        uA = uC; uB = uD; uC = uE; uD = uF;
        wA = wC; wB = wD; wC = wE; wD = wF;
        pB = pD; pC = pE; pD = pF;
    }

    if constexpr (MODE == 0) {
        #pragma unroll
        for (int off = 32; off; off >>= 1) {
            rmn = fminf(rmn, __shfl_down(rmn, off));
            rmx = fmaxf(rmx, __shfl_down(rmx, off));
            vmn = fminf(vmn, __shfl_down(vmn, off));
            vmx = fmaxf(vmx, __shfl_down(vmx, off));
        }
        __shared__ uint4 wred[4];
        if (lane == 0) {
            uint4 p;
            p.x = ford(rmn); p.y = ford(rmx); p.z = ford(vmn); p.w = ford(vmx);
            wred[threadIdx.x >> 6] = p;
        }
        __syncthreads();
        if (threadIdx.x == 0) {
            uint4 p = wred[0];
            #pragma unroll
            for (int w = 1; w < 4; ++w) {
                p.x = min(p.x, wred[w].x); p.y = max(p.y, wred[w].y);
                p.z = min(p.z, wred[w].z); p.w = max(p.w, wred[w].w);
            }
            partials[blockIdx.x] = p;
        }
    }
}

// Reduce NPBLK uint4 partials -> red[0..3]. One 256-thread block, 16 KB read.
__global__ __launch_bounds__(256)
void reduce_partials(const uint4* __restrict__ partials, unsigned int* __restrict__ red)
{
    __shared__ unsigned int wred[4][4];
    const int tid = threadIdx.x;
    unsigned int mn0 = 0xFFFFFFFFu, mx1 = 0u, mn2 = 0xFFFFFFFFu, mx3 = 0u;
    for (int i = tid; i < NPBLK; i += 256) {
        uint4 p = partials[i];
        mn0 = min(mn0, p.x); mx1 = max(mx1, p.y);
        mn2 = min(mn2, p.z); mx3 = max(mx3, p.w);
    }
    #pragma unroll
    for (int off = 32; off; off >>= 1) {
        mn0 = min(mn0, (unsigned)__shfl_down((int)mn0, off));
        mx1 = max(mx1, (unsigned)__shfl_down((int)mx1, off));
        mn2 = min(mn2, (unsigned)__shfl_down((int)mn2, off));
        mx3 = max(mx3, (unsigned)__shfl_down((int)mx3, off));
    }
    const int wave = tid >> 6;
    if ((tid & 63) == 0) {
        wred[wave][0] = mn0; wred[wave][1] = mx1;
        wred[wave][2] = mn2; wred[wave][3] = mx3;
    }
    __syncthreads();
    if (tid == 0) {
        unsigned int a0 = wred[0][0], a1 = wred[0][1], a2 = wred[0][2], a3 = wred[0][3];
        #pragma unroll
        for (int w = 1; w < 4; ++w) {
            a0 = min(a0, wred[w][0]); a1 = max(a1, wred[w][1]);
            a2 = min(a2, wred[w][2]); a3 = max(a3, wred[w][3]);
        }
        red[0] = a0; red[1] = a1; red[2] = a2; red[3] = a3;
    }
}

extern "C" void kernel_launch(void* const* d_in, const int* in_sizes, int n_in,
                              void* d_out, int out_size, void* d_ws, size_t ws_size,
                              hipStream_t stream) {
    const float* x = (const float*)d_in[0];
    float* out = (float*)d_out;
    unsigned int* red = (unsigned int*)d_ws;           // 4 uints
    uint4* partials = (uint4*)((char*)d_ws + 64);      // NPBLK uint4 = 16 KB

    band_kernel<0><<<dim3(NPBLK), 256, 0, stream>>>(x, out, partials, nullptr);
    reduce_partials<<<1, 256, 0, stream>>>(partials, red);
    band_kernel<1><<<dim3(NPBLK), 256, 0, stream>>>(x, out, nullptr, red);
}

// Round 11
// 54.506 us; speedup vs baseline: 1.2252x; 1.0659x over previous
//
#include <hip/hip_runtime.h>

#define IMG 224
#define PLANE (IMG * IMG)        // 50176
#define BANDROWS 8
#define NBANDS 28                // 28 * 8 = 224
#define NWAVES (256 * NBANDS)    // 7168 waves
#define NPBLK (NWAVES / 4)       // 1792 blocks of 4 waves

typedef float fl4 __attribute__((ext_vector_type(4)));

// ws layout: [0,16) red u32[4] | [64, +28KB) partials uint4[NPBLK]

// ---- ordered-uint mapping for float min/max ----
__device__ __forceinline__ unsigned int ford(float f) {
    unsigned int u = __float_as_uint(f);
    return (u & 0x80000000u) ? ~u : (u | 0x80000000u);
}
__device__ __forceinline__ float funord(unsigned int u) {
    unsigned int v = (u & 0x80000000u) ? (u & 0x7FFFFFFFu) : ~u;
    return __uint_as_float(v);
}

// One wave = one 8-row band of one image. Lane L owns cols 4L..4L+3 (L<56).
// No LDS / no barriers in the hot loop; horizontal halo via __shfl; vertical
// window via register rings; loads prefetched TWO row-pairs ahead.
// Border-exactness via closed-form corrections (validated R8).
// MODE 0: pass1 — min/max partials + ch0 write.
// MODE 1: pass2 — rec/ves channels write (reads red).
template<int MODE>
__global__ __launch_bounds__(256)
void band_kernel(const float* __restrict__ x, float* __restrict__ out,
                 uint4* __restrict__ partials, const unsigned int* __restrict__ red)
{
    const int wid  = (blockIdx.x << 2) + (threadIdx.x >> 6);
    const int lane = threadIdx.x & 63;
    const int img  = wid / NBANDS;
    const int band = wid - img * NBANDS;
    const int r0   = band * BANDROWS;
    const bool active = lane < 56;
    const int col = lane * 4;
    const float* xp = x + (size_t)img * 3 * PLANE;

    float rmin = 0.f, rsc = 0.f, vmin = 0.f, vsc = 0.f;
    if constexpr (MODE == 1) {
        rmin = funord(red[0]); const float rmax = funord(red[1]);
        vmin = funord(red[2]); const float vmax = funord(red[3]);
        rsc = 1.f / (rmax - rmin + 1e-6f);
        vsc = 1.f / (vmax - vmin + 1e-6f);
    }
    const float m0 = 0.485f, i0 = 1.f / 0.229f;
    const float m1 = 0.456f, i1 = 1.f / 0.224f;
    const float m2 = 0.406f, i2 = 1.f / 0.225f;

    float rmn = 3.4e38f, rmx = -3.4e38f, vmn = 3.4e38f, vmx = -3.4e38f;

    auto loadrow = [&](int gr) -> fl4 {
        fl4 v = (fl4)0.f;
        if (active && (unsigned)gr < (unsigned)IMG)
            v = *(const fl4*)(xp + gr * IMG + col);
        return v;
    };

    // horizontal prefilters: uu = [1,0,-2,0,1]*x, ww = [1,4,6,4,1]*x (zero-pad)
    auto pref = [&](fl4 p, fl4& uu, fl4& ww) {
        float cl1 = __shfl_up(p[3], 1);
        float cl2 = __shfl_up(p[2], 1);
        float cr1 = __shfl_down(p[0], 1);   // lane56 p==0 -> right pad free
        float cr2 = __shfl_down(p[1], 1);
        if (lane == 0) { cl1 = 0.f; cl2 = 0.f; }
        uu[0] = cl2 - 2.f*p[0] + p[2];
        uu[1] = cl1 - 2.f*p[1] + p[3];
        uu[2] = p[0] - 2.f*p[2] + cr1;
        uu[3] = p[1] - 2.f*p[3] + cr2;
        ww[0] = cl2 + 4.f*cl1 + 6.f*p[0] + 4.f*p[1] + p[2];
        ww[1] = cl1 + 4.f*p[0] + 6.f*p[1] + 4.f*p[2] + p[3];
        ww[2] = p[0] + 4.f*p[1] + 6.f*p[2] + 4.f*p[3] + cr1;
        ww[3] = p[1] + 4.f*p[2] + 6.f*p[3] + 4.f*cr1 + cr2;
    };

    auto haar2 = [&](fl4 xe, fl4 xo, fl4& re_, fl4& ro_) {
        #pragma unroll
        for (int q = 0; q < 2; ++q) {
            const float a = xe[2*q], b = xe[2*q+1], c = xo[2*q], d = xo[2*q+1];
            const float h0 = (a+b+c+d)*0.5f, h1 = (a-b+c-d)*0.5f;
            const float h2 = (a+b-c-d)*0.5f, h3 = (a-b-c+d)*0.5f;
            const float s0 = 0.1f*h0, s1 = 2.5f*h1, s2 = 2.5f*h2, s3 = 3.5f*h3;
            re_[2*q]   = (s0+s1+s2+s3)*0.5f;
            re_[2*q+1] = (s0-s1+s2-s3)*0.5f;
            ro_[2*q]   = (s0+s1-s2-s3)*0.5f;
            ro_[2*q+1] = (s0-s1-s2+s3)*0.5f;
        }
    };

    // emit one output row (closed-form border corrections, validated R8)
    auto dorow = [&](int gr, fl4 ua, fl4 ub, fl4 uc, fl4 ud, fl4 ue,
                     fl4 wa, fl4 wb, fl4 wc, fl4 wd, fl4 we,
                     fl4 pm1, fl4 p0c, fl4 pp1, fl4 recv) {
        fl4 t;
        #pragma unroll
        for (int j = 0; j < 4; ++j)
            t[j] = ua[j] + 4.f*ub[j] + 6.f*uc[j] + 4.f*ud[j] + ue[j]
                 + wa[j] - 2.f*wc[j] + we[j];
        const bool rb = (gr == 0) | (gr == IMG - 1);
        if (rb) {
            #pragma unroll
            for (int j = 0; j < 4; ++j) t[j] -= (uc[j] - wc[j]);
        }
        const float corr0 = -4.f*(pm1[0] + 2.f*p0c[0] + pp1[0]);
        const float corr3 = -4.f*(pm1[3] + 2.f*p0c[3] + pp1[3]);
        if (lane == 0)  t[0] -= corr0 + (rb ? 2.f*p0c[0] : 0.f);
        if (lane == 55) t[3] -= corr3 + (rb ? 2.f*p0c[3] : 0.f);
        fl4 ves;
        #pragma unroll
        for (int j = 0; j < 4; ++j) ves[j] = fabsf(t[j]);

        if (active) {
            if constexpr (MODE == 0) {
                #pragma unroll
                for (int j = 0; j < 4; ++j) {
                    rmn = fminf(rmn, recv[j]); rmx = fmaxf(rmx, recv[j]);
                    vmn = fminf(vmn, ves[j]);  vmx = fmaxf(vmx, ves[j]);
                }
                float* op = out + (size_t)img * 3 * PLANE + gr * IMG + col;
                fl4 o0;
                #pragma unroll
                for (int j = 0; j < 4; ++j) o0[j] = (p0c[j] - m0) * i0;
                __builtin_nontemporal_store(o0, (fl4*)op);
            } else {
                float* op = out + (size_t)img * 3 * PLANE + gr * IMG + col;
                fl4 o1, o2;
                #pragma unroll
                for (int j = 0; j < 4; ++j) {
                    o1[j] = ((recv[j] - rmin) * rsc - m1) * i1;
                    o2[j] = ((ves[j]  - vmin) * vsc - m2) * i2;
                }
                __builtin_nontemporal_store(o1, (fl4*)(op + PLANE));
                __builtin_nontemporal_store(o2, (fl4*)(op + 2 * PLANE));
            }
        }
    };

    // ---- warm-up rows r0-2 .. r0+1, plus depth-2 pair prefetch ----
    fl4 uA, uB, uC, uD, wA, wB, wC, wD, pB, pC, pD, nE, nF, nG, nH;
    {
        fl4 pA = loadrow(r0 - 2); pref(pA, uA, wA);
        pB = loadrow(r0 - 1); pref(pB, uB, wB);
        pC = loadrow(r0);     pref(pC, uC, wC);
        pD = loadrow(r0 + 1); pref(pD, uD, wD);
        nE = loadrow(r0 + 2);
        nF = loadrow(r0 + 3);
        nG = loadrow(r0 + 4);
        nH = loadrow(r0 + 5);
    }

    // ---- march 4 row-pairs, loads two pairs ahead ----
    for (int k = 0; k < BANDROWS / 2; ++k) {
        const int re = r0 + 2 * k;
        const fl4 pE = nE, pF = nF;
        nE = nG; nF = nH;
        if (k < BANDROWS / 2 - 2) {        // issue k+2's loads before compute
            nG = loadrow(re + 6);
            nH = loadrow(re + 7);
        }
        fl4 uE, wE; pref(pE, uE, wE);
        fl4 rec_e, rec_o; haar2(pC, pD, rec_e, rec_o);
        dorow(re,     uA, uB, uC, uD, uE, wA, wB, wC, wD, wE, pB, pC, pD, rec_e);
        fl4 uF, wF; pref(pF, uF, wF);
        dorow(re + 1, uB, uC, uD, uE, uF, wB, wC, wD, wE, wF, pC, pD, pE, rec_o);
        uA = uC; uB = uD; uC = uE; uD = uF;
        wA = wC; wB = wD; wC = wE; wD = wF;
        pB = pD; pC = pE; pD = pF;
    }

    if constexpr (MODE == 0) {
        #pragma unroll
        for (int off = 32; off; off >>= 1) {
            rmn = fminf(rmn, __shfl_down(rmn, off));
            rmx = fmaxf(rmx, __shfl_down(rmx, off));
            vmn = fminf(vmn, __shfl_down(vmn, off));
            vmx = fmaxf(vmx, __shfl_down(vmx, off));
        }
        __shared__ uint4 wred[4];
        if (lane == 0) {
            uint4 p;
            p.x = ford(rmn); p.y = ford(rmx); p.z = ford(vmn); p.w = ford(vmx);
            wred[threadIdx.x >> 6] = p;
        }
        __syncthreads();
        if (threadIdx.x == 0) {
            uint4 p = wred[0];
            #pragma unroll
            for (int w = 1; w < 4; ++w) {
                p.x = min(p.x, wred[w].x); p.y = max(p.y, wred[w].y);
                p.z = min(p.z, wred[w].z); p.w = max(p.w, wred[w].w);
            }
            partials[blockIdx.x] = p;
        }
    }
}

// Reduce NPBLK uint4 partials -> red[0..3]. One 256-thread block, 28 KB read.
__global__ __launch_bounds__(256)
void reduce_partials(const uint4* __restrict__ partials, unsigned int* __restrict__ red)
{
    __shared__ unsigned int wred[4][4];
    const int tid = threadIdx.x;
    unsigned int mn0 = 0xFFFFFFFFu, mx1 = 0u, mn2 = 0xFFFFFFFFu, mx3 = 0u;
    for (int i = tid; i < NPBLK; i += 256) {
        uint4 p = partials[i];
        mn0 = min(mn0, p.x); mx1 = max(mx1, p.y);
        mn2 = min(mn2, p.z); mx3 = max(mx3, p.w);
    }
    #pragma unroll
    for (int off = 32; off; off >>= 1) {
        mn0 = min(mn0, (unsigned)__shfl_down((int)mn0, off));
        mx1 = max(mx1, (unsigned)__shfl_down((int)mx1, off));
        mn2 = min(mn2, (unsigned)__shfl_down((int)mn2, off));
        mx3 = max(mx3, (unsigned)__shfl_down((int)mx3, off));
    }
    const int wave = tid >> 6;
    if ((tid & 63) == 0) {
        wred[wave][0] = mn0; wred[wave][1] = mx1;
        wred[wave][2] = mn2; wred[wave][3] = mx3;
    }
    __syncthreads();
    if (tid == 0) {
        unsigned int a0 = wred[0][0], a1 = wred[0][1], a2 = wred[0][2], a3 = wred[0][3];
        #pragma unroll
        for (int w = 1; w < 4; ++w) {
            a0 = min(a0, wred[w][0]); a1 = max(a1, wred[w][1]);
            a2 = min(a2, wred[w][2]); a3 = max(a3, wred[w][3]);
        }
        red[0] = a0; red[1] = a1; red[2] = a2; red[3] = a3;
    }
}

extern "C" void kernel_launch(void* const* d_in, const int* in_sizes, int n_in,
                              void* d_out, int out_size, void* d_ws, size_t ws_size,
                              hipStream_t stream) {
    const float* x = (const float*)d_in[0];
    float* out = (float*)d_out;
    unsigned int* red = (unsigned int*)d_ws;           // 4 uints
    uint4* partials = (uint4*)((char*)d_ws + 64);      // NPBLK uint4 = 28 KB

    band_kernel<0><<<dim3(NPBLK), 256, 0, stream>>>(x, out, partials, nullptr);
    reduce_partials<<<1, 256, 0, stream>>>(partials, red);
    band_kernel<1><<<dim3(NPBLK), 256, 0, stream>>>(x, out, nullptr, red);
}

// Round 12
// 53.934 us; speedup vs baseline: 1.2382x; 1.0106x over previous
//
#include <hip/hip_runtime.h>

#define IMG 224
#define PLANE (IMG * IMG)        // 50176
#define BANDROWS 8
#define NBANDS 28                // 28 * 8 = 224
#define NWAVES (256 * NBANDS)    // 7168 waves
#define NPBLK (NWAVES / 4)       // 1792 blocks of 4 waves

typedef float fl4 __attribute__((ext_vector_type(4)));

// ws layout: [64, +28KB) partials uint4[NPBLK]

// ---- ordered-uint mapping for float min/max ----
__device__ __forceinline__ unsigned int ford(float f) {
    unsigned int u = __float_as_uint(f);
    return (u & 0x80000000u) ? ~u : (u | 0x80000000u);
}
__device__ __forceinline__ float funord(unsigned int u) {
    unsigned int v = (u & 0x80000000u) ? (u & 0x7FFFFFFFu) : ~u;
    return __uint_as_float(v);
}

// One wave = one 8-row band of one image. Lane L owns cols 4L..4L+3 (L<56).
// No LDS/barriers in the hot loop; horizontal halo via __shfl; vertical window
// via register rings; loads prefetched two row-pairs ahead. Border-exactness
// via closed-form corrections (validated R8).
// MODE 0: pass1 — min/max partials + ch0 write.
// MODE 1: pass2 — per-block partial-reduce preamble, then rec/ves writes.
template<int MODE>
__global__ __launch_bounds__(256)
void band_kernel(const float* __restrict__ x, float* __restrict__ out,
                 uint4* __restrict__ partials)
{
    const int wid  = (blockIdx.x << 2) + (threadIdx.x >> 6);
    const int lane = threadIdx.x & 63;
    const int img  = wid / NBANDS;
    const int band = wid - img * NBANDS;
    const int r0   = band * BANDROWS;
    const bool active = lane < 56;
    const int col = lane * 4;
    const float* xp = x + (size_t)img * 3 * PLANE;

    float rmin = 0.f, rsc = 0.f, vmin = 0.f, vsc = 0.f;
    if constexpr (MODE == 1) {
        // ---- fused reduce preamble: all 256 threads reduce NPBLK partials ----
        __shared__ unsigned int sred[4][4];
        __shared__ float s_scal[4];
        const int tid = threadIdx.x;
        unsigned int mn0 = 0xFFFFFFFFu, mx1 = 0u, mn2 = 0xFFFFFFFFu, mx3 = 0u;
        for (int i = tid; i < NPBLK; i += 256) {
            uint4 p = partials[i];
            mn0 = min(mn0, p.x); mx1 = max(mx1, p.y);
            mn2 = min(mn2, p.z); mx3 = max(mx3, p.w);
        }
        #pragma unroll
        for (int off = 32; off; off >>= 1) {
            mn0 = min(mn0, (unsigned)__shfl_down((int)mn0, off));
            mx1 = max(mx1, (unsigned)__shfl_down((int)mx1, off));
            mn2 = min(mn2, (unsigned)__shfl_down((int)mn2, off));
            mx3 = max(mx3, (unsigned)__shfl_down((int)mx3, off));
        }
        if (lane == 0) {
            const int w = tid >> 6;
            sred[w][0] = mn0; sred[w][1] = mx1; sred[w][2] = mn2; sred[w][3] = mx3;
        }
        __syncthreads();
        if (tid == 0) {
            unsigned int a0 = sred[0][0], a1 = sred[0][1], a2 = sred[0][2], a3 = sred[0][3];
            #pragma unroll
            for (int w = 1; w < 4; ++w) {
                a0 = min(a0, sred[w][0]); a1 = max(a1, sred[w][1]);
                a2 = min(a2, sred[w][2]); a3 = max(a3, sred[w][3]);
            }
            const float rmn_ = funord(a0), rmx_ = funord(a1);
            const float vmn_ = funord(a2), vmx_ = funord(a3);
            s_scal[0] = rmn_;
            s_scal[1] = 1.f / (rmx_ - rmn_ + 1e-6f);
            s_scal[2] = vmn_;
            s_scal[3] = 1.f / (vmx_ - vmn_ + 1e-6f);
        }
        __syncthreads();
        rmin = s_scal[0]; rsc = s_scal[1]; vmin = s_scal[2]; vsc = s_scal[3];
    }
    const float m0 = 0.485f, i0 = 1.f / 0.229f;
    const float m1 = 0.456f, i1 = 1.f / 0.224f;
    const float m2 = 0.406f, i2 = 1.f / 0.225f;

    float rmn = 3.4e38f, rmx = -3.4e38f, vmn = 3.4e38f, vmx = -3.4e38f;

    auto loadrow = [&](int gr) -> fl4 {
        fl4 v = (fl4)0.f;
        if (active && (unsigned)gr < (unsigned)IMG)
            v = *(const fl4*)(xp + gr * IMG + col);
        return v;
    };

    // horizontal prefilters: uu = [1,0,-2,0,1]*x, ww = [1,4,6,4,1]*x (zero-pad)
    auto pref = [&](fl4 p, fl4& uu, fl4& ww) {
        float cl1 = __shfl_up(p[3], 1);
        float cl2 = __shfl_up(p[2], 1);
        float cr1 = __shfl_down(p[0], 1);   // lane56 p==0 -> right pad free
        float cr2 = __shfl_down(p[1], 1);
        if (lane == 0) { cl1 = 0.f; cl2 = 0.f; }
        uu[0] = cl2 - 2.f*p[0] + p[2];
        uu[1] = cl1 - 2.f*p[1] + p[3];
        uu[2] = p[0] - 2.f*p[2] + cr1;
        uu[3] = p[1] - 2.f*p[3] + cr2;
        ww[0] = cl2 + 4.f*cl1 + 6.f*p[0] + 4.f*p[1] + p[2];
        ww[1] = cl1 + 4.f*p[0] + 6.f*p[1] + 4.f*p[2] + p[3];
        ww[2] = p[0] + 4.f*p[1] + 6.f*p[2] + 4.f*p[3] + cr1;
        ww[3] = p[1] + 4.f*p[2] + 6.f*p[3] + 4.f*cr1 + cr2;
    };

    auto haar2 = [&](fl4 xe, fl4 xo, fl4& re_, fl4& ro_) {
        #pragma unroll
        for (int q = 0; q < 2; ++q) {
            const float a = xe[2*q], b = xe[2*q+1], c = xo[2*q], d = xo[2*q+1];
            const float h0 = (a+b+c+d)*0.5f, h1 = (a-b+c-d)*0.5f;
            const float h2 = (a+b-c-d)*0.5f, h3 = (a-b-c+d)*0.5f;
            const float s0 = 0.1f*h0, s1 = 2.5f*h1, s2 = 2.5f*h2, s3 = 3.5f*h3;
            re_[2*q]   = (s0+s1+s2+s3)*0.5f;
            re_[2*q+1] = (s0-s1+s2-s3)*0.5f;
            ro_[2*q]   = (s0+s1-s2-s3)*0.5f;
            ro_[2*q+1] = (s0-s1-s2+s3)*0.5f;
        }
    };

    // emit one output row (closed-form border corrections, validated R8)
    auto dorow = [&](int gr, fl4 ua, fl4 ub, fl4 uc, fl4 ud, fl4 ue,
                     fl4 wa, fl4 wb, fl4 wc, fl4 wd, fl4 we,
                     fl4 pm1, fl4 p0c, fl4 pp1, fl4 recv) {
        fl4 t;
        #pragma unroll
        for (int j = 0; j < 4; ++j)
            t[j] = ua[j] + 4.f*ub[j] + 6.f*uc[j] + 4.f*ud[j] + ue[j]
                 + wa[j] - 2.f*wc[j] + we[j];
        const bool rb = (gr == 0) | (gr == IMG - 1);
        if (rb) {
            #pragma unroll
            for (int j = 0; j < 4; ++j) t[j] -= (uc[j] - wc[j]);
        }
        const float corr0 = -4.f*(pm1[0] + 2.f*p0c[0] + pp1[0]);
        const float corr3 = -4.f*(pm1[3] + 2.f*p0c[3] + pp1[3]);
        if (lane == 0)  t[0] -= corr0 + (rb ? 2.f*p0c[0] : 0.f);
        if (lane == 55) t[3] -= corr3 + (rb ? 2.f*p0c[3] : 0.f);
        fl4 ves;
        #pragma unroll
        for (int j = 0; j < 4; ++j) ves[j] = fabsf(t[j]);

        if (active) {
            if constexpr (MODE == 0) {
                #pragma unroll
                for (int j = 0; j < 4; ++j) {
                    rmn = fminf(rmn, recv[j]); rmx = fmaxf(rmx, recv[j]);
                    vmn = fminf(vmn, ves[j]);  vmx = fmaxf(vmx, ves[j]);
                }
                float* op = out + (size_t)img * 3 * PLANE + gr * IMG + col;
                fl4 o0;
                #pragma unroll
                for (int j = 0; j < 4; ++j) o0[j] = (p0c[j] - m0) * i0;
                __builtin_nontemporal_store(o0, (fl4*)op);
            } else {
                float* op = out + (size_t)img * 3 * PLANE + gr * IMG + col;
                fl4 o1, o2;
                #pragma unroll
                for (int j = 0; j < 4; ++j) {
                    o1[j] = ((recv[j] - rmin) * rsc - m1) * i1;
                    o2[j] = ((ves[j]  - vmin) * vsc - m2) * i2;
                }
                __builtin_nontemporal_store(o1, (fl4*)(op + PLANE));
                __builtin_nontemporal_store(o2, (fl4*)(op + 2 * PLANE));
            }
        }
    };

    // ---- warm-up rows r0-2 .. r0+1, plus depth-2 pair prefetch ----
    fl4 uA, uB, uC, uD, wA, wB, wC, wD, pB, pC, pD, nE, nF, nG, nH;
    {
        fl4 pA = loadrow(r0 - 2); pref(pA, uA, wA);
        pB = loadrow(r0 - 1); pref(pB, uB, wB);
        pC = loadrow(r0);     pref(pC, uC, wC);
        pD = loadrow(r0 + 1); pref(pD, uD, wD);
        nE = loadrow(r0 + 2);
        nF = loadrow(r0 + 3);
        nG = loadrow(r0 + 4);
        nH = loadrow(r0 + 5);
    }

    // ---- march 4 row-pairs, loads two pairs ahead ----
    for (int k = 0; k < BANDROWS / 2; ++k) {
        const int re = r0 + 2 * k;
        const fl4 pE = nE, pF = nF;
        nE = nG; nF = nH;
        if (k < BANDROWS / 2 - 2) {        // issue k+2's loads before compute
            nG = loadrow(re + 6);
            nH = loadrow(re + 7);
        }
        fl4 uE, wE; pref(pE, uE, wE);
        fl4 rec_e, rec_o; haar2(pC, pD, rec_e, rec_o);
        dorow(re,     uA, uB, uC, uD, uE, wA, wB, wC, wD, wE, pB, pC, pD, rec_e);
        fl4 uF, wF; pref(pF, uF, wF);
        dorow(re + 1, uB, uC, uD, uE, uF, wB, wC, wD, wE, wF, pC, pD, pE, rec_o);
        uA = uC; uB = uD; uC = uE; uD = uF;
        wA = wC; wB = wD; wC = wE; wD = wF;
        pB = pD; pC = pE; pD = pF;
    }

    if constexpr (MODE == 0) {
        #pragma unroll
        for (int off = 32; off; off >>= 1) {
            rmn = fminf(rmn, __shfl_down(rmn, off));
            rmx = fmaxf(rmx, __shfl_down(rmx, off));
            vmn = fminf(vmn, __shfl_down(vmn, off));
            vmx = fmaxf(vmx, __shfl_down(vmx, off));
        }
        __shared__ uint4 wred[4];
        if (lane == 0) {
            uint4 p;
            p.x = ford(rmn); p.y = ford(rmx); p.z = ford(vmn); p.w = ford(vmx);
            wred[threadIdx.x >> 6] = p;
        }
        __syncthreads();
        if (threadIdx.x == 0) {
            uint4 p = wred[0];
            #pragma unroll
            for (int w = 1; w < 4; ++w) {
                p.x = min(p.x, wred[w].x); p.y = max(p.y, wred[w].y);
                p.z = min(p.z, wred[w].z); p.w = max(p.w, wred[w].w);
            }
            partials[blockIdx.x] = p;
        }
    }
}

extern "C" void kernel_launch(void* const* d_in, const int* in_sizes, int n_in,
                              void* d_out, int out_size, void* d_ws, size_t ws_size,
                              hipStream_t stream) {
    const float* x = (const float*)d_in[0];
    float* out = (float*)d_out;
    uint4* partials = (uint4*)((char*)d_ws + 64);      // NPBLK uint4 = 28 KB

    band_kernel<0><<<dim3(NPBLK), 256, 0, stream>>>(x, out, partials);
    band_kernel<1><<<dim3(NPBLK), 256, 0, stream>>>(x, out, partials);
}